// Round 10
// baseline (8377.586 us; speedup 1.0000x reference)
//
#include <hip/hip_runtime.h>

typedef _Float16 f16x8 __attribute__((ext_vector_type(8)));
typedef float    f32x4 __attribute__((ext_vector_type(4)));

// DPP quad-perm lane exchange (VALU, no LDS): 0xB1=xor1, 0x4E=xor2, 0x1B=xor3
template <int CTRL>
__device__ __forceinline__ float dpp_q(float v) {
    int i = __builtin_bit_cast(int, v);
    int r = __builtin_amdgcn_update_dpp(0, i, CTRL, 0xF, 0xF, true);
    return __builtin_bit_cast(float, r);
}

// Barrier draining ONLY LDS ops (lgkmcnt): global prefetches stay in flight.
#define BARRIER() asm volatile("s_waitcnt lgkmcnt(0)\n\ts_barrier" ::: "memory")

// 96-wide f32 dot of one LDS history row against w_dense.
__device__ __forceinline__ float head_dot(const float* hrow, const float* wdp) {
    const float4* hr = reinterpret_cast<const float4*>(hrow);
    const float4* wv = reinterpret_cast<const float4*>(wdp);
    float a0 = 0.f, a1 = 0.f, a2 = 0.f, a3 = 0.f;
    #pragma unroll
    for (int k = 0; k < 24; k += 4) {
        float4 ha = hr[k], hb = hr[k + 1], hc = hr[k + 2], hd = hr[k + 3];
        float4 wa = wv[k], wb = wv[k + 1], wc = wv[k + 2], wd = wv[k + 3];
        a0 = fmaf(ha.w, wa.w, fmaf(ha.z, wa.z, fmaf(ha.y, wa.y, fmaf(ha.x, wa.x, a0))));
        a1 = fmaf(hb.w, wb.w, fmaf(hb.z, wb.z, fmaf(hb.y, wb.y, fmaf(hb.x, wb.x, a1))));
        a2 = fmaf(hc.w, wc.w, fmaf(hc.z, wc.z, fmaf(hc.y, wc.y, fmaf(hc.x, wc.x, a2))));
        a3 = fmaf(hd.w, wd.w, fmaf(hd.z, wd.z, fmaf(hd.y, wd.y, fmaf(hd.x, wd.x, a3))));
    }
    return (a0 + a1) + (a2 + a3);
}

// 7 waves: 0..5 gate waves, 6 = head.
// Gate wave w: 4 MFMA tile-chains ct=0..3 (gate classes i,f,g,o), rows
// 96*ct + 16*w .. +16, K=96 in 3 steps of 32. Every lane reads the SAME
// h-chunk for its k-group -> B[k][col]=h[k] for all cols -> every lane's D
// holds valid pre-activations (col-replicated). Lane L = (uq<<2)|g then
// selects its gate pre = D[tile g][reg (uq&3)] (note uq>>2 == L>>4 == its
// k-group, so the row matches) via a 15-cndmask tree. Weights and xb are
// PRE-SCALED by -log2e (sigmoid) / -2log2e (tanh) so D is exp2-ready; xb
// enters via the MFMA C-operand. Activation: ONE exp2 + ONE rcp per wave.
// Quad DPP gathers i/f/g/o; g==0 lane owns c/h of unit 16*w + uq.
__global__ __launch_bounds__(448)
void lstm_fused(
    const float* __restrict__ x,        // [B,T]
    const float* __restrict__ w_ih,     // [384]
    const float* __restrict__ w_hh,     // [384,96]
    const float* __restrict__ b_ih,     // [384]
    const float* __restrict__ b_hh,     // [384]
    const float* __restrict__ w_dense,  // [96]
    const float* __restrict__ b_dense,  // [1]
    float* __restrict__ out,            // [B,T]
    int T)
{
    const int tid  = threadIdx.x;    // 0..447
    const int lane = tid & 63;
    const int wv   = tid >> 6;       // 0..5 gate, 6 head

    __shared__ __align__(16) _Float16 hbuf[2][96];   // double-buffered h (f16)
    __shared__ __align__(16) float hist[2][64][100]; // h history for the head

    if (tid < 96) { hbuf[0][tid] = (_Float16)0.f; hbuf[1][tid] = (_Float16)0.f; }

    const float* xrow = x + (size_t)blockIdx.x * T;
    float*       orow = out + (size_t)blockIdx.x * T;

    __syncthreads();

    if (wv < 6) {
        const int g    = lane & 3;       // gate class of THIS lane (quad layout)
        const int uq   = lane >> 2;      // unit-within-wave 0..15
        const int u    = wv * 16 + uq;   // global unit 0..95
        const int arow = lane & 15;      // A-fragment row within tile
        const int kg   = lane >> 4;      // k-group 0..3 (rows kg*4..kg*4+3 in D)

        // A-fragments, pre-scaled by the exp2 activation constant of the tile.
        f16x8 A_[4][3];
        #pragma unroll
        for (int ct = 0; ct < 4; ++ct) {
            const float nk = (ct == 2) ? -2.885390082f : -1.442695041f;
            const float* rp = w_hh + (size_t)(96 * ct + 16 * wv + arow) * 96 + kg * 8;
            #pragma unroll
            for (int kt = 0; kt < 3; ++kt)
                #pragma unroll
                for (int i = 0; i < 8; ++i)
                    A_[ct][kt][i] = (_Float16)(nk * rp[kt * 32 + i]);
        }

        // Per-lane xb constants (scaled) for the D rows this lane holds:
        // tile ct, reg q -> row kg*4+q -> j = 96*ct + 16*wv + kg*4 + q.
        float wihs[4][4], biass[4][4];
        #pragma unroll
        for (int ct = 0; ct < 4; ++ct) {
            const float nk = (ct == 2) ? -2.885390082f : -1.442695041f;
            #pragma unroll
            for (int q = 0; q < 4; ++q) {
                int j = 96 * ct + 16 * wv + kg * 4 + q;
                wihs[ct][q]  = nk * w_ih[j];
                biass[ct][q] = nk * (b_ih[j] + b_hh[j]);
            }
        }

        // Activation shape constants for THIS lane's own gate class g.
        const float m1 = (g == 2) ? 2.f : 1.f;
        const float d1 = (g == 2) ? -1.f : 0.f;
        const bool  g1 = (g & 1) != 0, g2 = (g & 2) != 0;
        const bool  u1 = (uq & 1) != 0, u2 = (uq & 2) != 0;

        float c  = 0.f;
        float xs = xrow[0];

        #pragma unroll 1
        for (int t = 0; t < T; ++t) {
            int tn = (t + 1 < T) ? t + 1 : T - 1;
            float xs_n = xrow[tn];                 // off-chain (vmcnt) prefetch

            // D init = scaled xb (independent of LDS -> fills b128 latency).
            f32x4 D0, D1, D2, D3;
            #pragma unroll
            for (int q = 0; q < 4; ++q) {
                D0[q] = fmaf(xs, wihs[0][q], biass[0][q]);
                D1[q] = fmaf(xs, wihs[1][q], biass[1][q]);
                D2[q] = fmaf(xs, wihs[2][q], biass[2][q]);
                D3[q] = fmaf(xs, wihs[3][q], biass[3][q]);
            }

            const _Float16* hb = hbuf[(t & 1) ^ 1];
            f16x8 B0 = *(const f16x8*)&hb[ 0 + kg * 8];
            f16x8 B1 = *(const f16x8*)&hb[32 + kg * 8];
            f16x8 B2 = *(const f16x8*)&hb[64 + kg * 8];

            D0 = __builtin_amdgcn_mfma_f32_16x16x32_f16(A_[0][0], B0, D0, 0, 0, 0);
            D1 = __builtin_amdgcn_mfma_f32_16x16x32_f16(A_[1][0], B0, D1, 0, 0, 0);
            D2 = __builtin_amdgcn_mfma_f32_16x16x32_f16(A_[2][0], B0, D2, 0, 0, 0);
            D3 = __builtin_amdgcn_mfma_f32_16x16x32_f16(A_[3][0], B0, D3, 0, 0, 0);
            D0 = __builtin_amdgcn_mfma_f32_16x16x32_f16(A_[0][1], B1, D0, 0, 0, 0);
            D1 = __builtin_amdgcn_mfma_f32_16x16x32_f16(A_[1][1], B1, D1, 0, 0, 0);
            D2 = __builtin_amdgcn_mfma_f32_16x16x32_f16(A_[2][1], B1, D2, 0, 0, 0);
            D3 = __builtin_amdgcn_mfma_f32_16x16x32_f16(A_[3][1], B1, D3, 0, 0, 0);
            D0 = __builtin_amdgcn_mfma_f32_16x16x32_f16(A_[0][2], B2, D0, 0, 0, 0);
            D1 = __builtin_amdgcn_mfma_f32_16x16x32_f16(A_[1][2], B2, D1, 0, 0, 0);
            D2 = __builtin_amdgcn_mfma_f32_16x16x32_f16(A_[2][2], B2, D2, 0, 0, 0);
            D3 = __builtin_amdgcn_mfma_f32_16x16x32_f16(A_[3][2], B2, D3, 0, 0, 0);

            // Select this lane's gate pre-activation: D[g][(uq&3)].
            float s0 = g1 ? (g2 ? D3[0] : D1[0]) : (g2 ? D2[0] : D0[0]);
            float s1 = g1 ? (g2 ? D3[1] : D1[1]) : (g2 ? D2[1] : D0[1]);
            float s2 = g1 ? (g2 ? D3[2] : D1[2]) : (g2 ? D2[2] : D0[2]);
            float s3 = g1 ? (g2 ? D3[3] : D1[3]) : (g2 ? D2[3] : D0[3]);
            float pre = u1 ? (u2 ? s3 : s1) : (u2 ? s2 : s0);

            // act = m1 * rcp(1 + exp2(pre)) + d1  (scale already baked in)
            float actv = fmaf(m1, __builtin_amdgcn_rcpf(1.f + __builtin_exp2f(pre)), d1);

            // gather the other 3 gates of this unit via quad-perm DPP (VALU)
            float x1 = dpp_q<0xB1>(actv);   // lane^1
            float x2 = dpp_q<0x4E>(actv);   // lane^2
            float x3 = dpp_q<0x1B>(actv);   // lane^3

            if (g == 0) {   // i-lane owns unit u: actv=i, x1=f, x2=g, x3=o
                c = fmaf(x1, c, actv * x2);
                float th = fmaf(2.f, __builtin_amdgcn_rcpf(1.f + __builtin_exp2f(c * -2.885390082f)), -1.f);
                float h  = x3 * th;
                hbuf[t & 1][u] = (_Float16)h;          // matvec path (f16)
                hist[(t >> 6) & 1][t & 63][u] = h;     // head path (f32)
            }
            BARRIER();
            xs = xs_n;
        }
    } else {
        // ---- head wave: one burst of 64 outputs per 64-step window ----
        const float bd = b_dense[0];
        #pragma unroll 1
        for (int t = 0; t < T; ++t) {
            if (t && (t & 63) == 0) {
                const int buf = ((t >> 6) - 1) & 1;    // completed window
                float a = head_dot(&hist[buf][lane][0], w_dense);
                orow[t - 64 + lane] = a + bd;
            }
            BARRIER();
        }
        // tail: rows [T0, T)
        const int T0 = ((T - 1) >> 6) << 6;
        if (lane < T - T0) {
            const int buf = (T0 >> 6) & 1;
            float a = head_dot(&hist[buf][lane][0], w_dense);
            orow[T0 + lane] = a + bd;
        }
    }
}

extern "C" void kernel_launch(void* const* d_in, const int* in_sizes, int n_in,
                              void* d_out, int out_size, void* d_ws, size_t ws_size,
                              hipStream_t stream) {
    const float* x   = (const float*)d_in[0];
    const float* wih = (const float*)d_in[1];
    const float* whh = (const float*)d_in[2];
    const float* bih = (const float*)d_in[3];
    const float* bhh = (const float*)d_in[4];
    const float* wd  = (const float*)d_in[5];
    const float* bd  = (const float*)d_in[6];
    float* out = (float*)d_out;

    const int B = 32;
    const int T = in_sizes[0] / B;   // x is [B,T,1]

    lstm_fused<<<dim3(B), dim3(448), 0, stream>>>(x, wih, whh, bih, bhh, wd, bd, out, T);
}